// Round 2
// baseline (6889.393 us; speedup 1.0000x reference)
//
#include <hip/hip_runtime.h>

// ---------------------------------------------------------------------------
// StackedBidirectionalLstm  (B=32, T=512, IN=512, H=512, LAYERS=2, bidir, highway)
//
// Plan:
//   px[d] = A @ Wx[d]^T  (bf16 MFMA GEMM, A = x or layer-0 output)
//   then 512 per-timestep kernels per layer: ps = h@Wh (bf16 MFMA, K-split over
//   4 waves + LDS reduce), gates/c/h in fp32. h broadcast double-buffered bf16.
//   Kernel-launch boundary = grid barrier between timesteps.
//
// Memory (ws_size unknown -> keep ws small; use d_out as scratch for
// transients, fully overwritten by final outputs):
//   ws layout (bytes), total 212,074,496 (~202.3 MiB):
//     px   @ 0          201,326,592  ([2][16384][3072] bf16)
//     whp  @ 201326592   10,485,760  (packed Wh fragments, 4 x 1,310,720 elems)
//     hbf  @ 211812352      131,072  (2 buf x 2 dir x 32 x 512 bf16)
//     cbuf @ 211943424      131,072  (2 dir x 32 x 512 f32)
//   d_out scratch (64.5 MiB available):
//     phase A: xbf @ +0 (16 MiB), wxt0 @ +16 MiB (6 MiB), wxt1 @ +32 MiB (12 MiB)
//     phase B: a1bf @ +0 (32 MiB)  [xbf/wxt0 dead; ends where wxt1 begins]
//     layer-1 recurrence overwrites all of d_out with the true outputs.
// ---------------------------------------------------------------------------

typedef float f32x4 __attribute__((ext_vector_type(4)));
typedef __bf16 bf16x8 __attribute__((ext_vector_type(8)));
typedef unsigned short us8 __attribute__((ext_vector_type(8)));
typedef unsigned short us4 __attribute__((ext_vector_type(4)));

__device__ __forceinline__ unsigned short f2bf(float f) {
  unsigned int u = __float_as_uint(f);
  u += 0x7FFFu + ((u >> 16) & 1u);            // round-to-nearest-even
  return (unsigned short)(u >> 16);
}
__device__ __forceinline__ float bf2f(unsigned short h) {
  return __uint_as_float(((unsigned int)h) << 16);
}
__device__ __forceinline__ float sigf(float x) { return 1.0f / (1.0f + __expf(-x)); }
__device__ __forceinline__ float tanh_(float x) { return 2.0f / (1.0f + __expf(-2.0f * x)) - 1.0f; }

#define MFMA(a, b, c) __builtin_amdgcn_mfma_f32_16x16x32_bf16((a), (b), (c), 0, 0, 0)
#define GLOAD_LDS(gp, lp)                                                           \
  __builtin_amdgcn_global_load_lds(                                                 \
      (const __attribute__((address_space(1))) void*)(gp),                          \
      (__attribute__((address_space(3))) void*)(lp), 16, 0, 0)

// --------------------------- prep kernels ----------------------------------

__global__ void k_convert_x(const float* __restrict__ x, unsigned short* __restrict__ xb, int n4) {
  int i = blockIdx.x * blockDim.x + threadIdx.x;
  if (i < n4) {
    float4 v = ((const float4*)x)[i];
    us4 o;
    o[0] = f2bf(v.x); o[1] = f2bf(v.y); o[2] = f2bf(v.z); o[3] = f2bf(v.w);
    ((us4*)xb)[i] = o;
  }
}

// WxT[n][k] = bf16(Wx[k][n]); y = layer*2+dir
__global__ void k_pack_wxT(const float* __restrict__ W0, const float* __restrict__ W1,
                           const float* __restrict__ W2, const float* __restrict__ W3,
                           unsigned short* __restrict__ o01, unsigned short* __restrict__ o23) {
  int y = blockIdx.y;
  int K = (y >> 1) ? 1024 : 512;
  const float* W = (y == 0) ? W0 : (y == 1) ? W1 : (y == 2) ? W2 : W3;
  unsigned short* o = (y >> 1) ? (o23 + (size_t)(y & 1) * 3072 * 1024)
                               : (o01 + (size_t)(y & 1) * 3072 * 512);
  int n = blockIdx.x * blockDim.x + threadIdx.x;
  if (n < 3072) {
    for (int k = 0; k < K; ++k) o[(size_t)n * K + k] = f2bf(W[(size_t)k * 3072 + n]);
  }
}

// Pack Wh (512x2560 f32) into MFMA B-fragments:
// out[(((g*32+ns)*16+ks)*64+lane)*8+e] = Wh[ks*32+(lane>>4)*8+e][g*512+ns*16+(lane&15)]
__global__ void k_pack_whp(const float* __restrict__ W0, const float* __restrict__ W1,
                           const float* __restrict__ W2, const float* __restrict__ W3,
                           unsigned short* __restrict__ out) {
  int y = blockIdx.y;
  const float* W = (y == 0) ? W0 : (y == 1) ? W1 : (y == 2) ? W2 : W3;
  unsigned short* o = out + (size_t)y * 1310720;
  int v = blockIdx.x * 256 + threadIdx.x;   // < 163840
  int lane = v & 63, ks = (v >> 6) & 15, ns = (v >> 10) & 31, g = v >> 15;
  int col = g * 512 + ns * 16 + (lane & 15);
  int kb = ks * 32 + ((lane >> 4) << 3);
  us8 vec;
#pragma unroll
  for (int e = 0; e < 8; ++e) vec[e] = f2bf(W[(size_t)(kb + e) * 2560 + col]);
  *(us8*)&o[(size_t)v * 8] = vec;
}

// --------------------------- bf16 GEMM -------------------------------------
// C[16384][3072] = A[16384][K] @ Bt[3072][K]^T, per blockIdx.z (direction).
// 128x128 tile, BK=32, 4 waves (2x2 of 64x64), global_load_lds(16B),
// quarter XOR-swizzle within each 64B LDS row.
__global__ __launch_bounds__(256) void k_gemm(const unsigned short* __restrict__ A,
                                              const unsigned short* __restrict__ BtBase,
                                              unsigned short* __restrict__ CBase, int K) {
  __shared__ __align__(128) unsigned short As[128 * 32];
  __shared__ __align__(128) unsigned short Bs[128 * 32];
  const unsigned short* Bt = BtBase + (size_t)blockIdx.z * 3072 * K;
  unsigned short* C = CBase + (size_t)blockIdx.z * 16384 * 3072;
  int tid = threadIdx.x;
  int w = tid >> 6, l = tid & 63;
  int m0 = blockIdx.x * 128, n0 = blockIdx.y * 128;
  int wr = (w >> 1) * 64, wc = (w & 1) * 64;
  f32x4 acc[4][4];
#pragma unroll
  for (int i = 0; i < 4; ++i)
#pragma unroll
    for (int j = 0; j < 4; ++j) acc[i][j] = (f32x4){0.f, 0.f, 0.f, 0.f};

  for (int k0 = 0; k0 < K; k0 += 32) {
    __syncthreads();
#pragma unroll
    for (int half = 0; half < 2; ++half) {
      int r = w * 32 + half * 16 + (l >> 2);     // row within tile
      int gq = (l & 3) ^ (r & 3);                // swizzled source quarter
      GLOAD_LDS(A + (size_t)(m0 + r) * K + k0 + gq * 8, &As[(w * 32 + half * 16) * 32]);
      GLOAD_LDS(Bt + (size_t)(n0 + r) * K + k0 + gq * 8, &Bs[(w * 32 + half * 16) * 32]);
    }
    __syncthreads();
    bf16x8 af[4], bfr[4];
#pragma unroll
    for (int mi = 0; mi < 4; ++mi) {
      int r = wr + mi * 16 + (l & 15);
      int q = (l >> 4) ^ (r & 3);
      af[mi] = __builtin_bit_cast(bf16x8, *(const us8*)&As[r * 32 + q * 8]);
    }
#pragma unroll
    for (int ni = 0; ni < 4; ++ni) {
      int r = wc + ni * 16 + (l & 15);
      int q = (l >> 4) ^ (r & 3);
      bfr[ni] = __builtin_bit_cast(bf16x8, *(const us8*)&Bs[r * 32 + q * 8]);
    }
#pragma unroll
    for (int mi = 0; mi < 4; ++mi)
#pragma unroll
      for (int ni = 0; ni < 4; ++ni) acc[mi][ni] = MFMA(af[mi], bfr[ni], acc[mi][ni]);
  }
#pragma unroll
  for (int mi = 0; mi < 4; ++mi)
#pragma unroll
    for (int ni = 0; ni < 4; ++ni)
#pragma unroll
      for (int r4 = 0; r4 < 4; ++r4) {
        int row = m0 + wr + mi * 16 + (l >> 4) * 4 + r4;
        int col = n0 + wc + ni * 16 + (l & 15);
        C[(size_t)row * 3072 + col] = f2bf(acc[mi][ni][r4]);
      }
}

// --------------------------- LSTM step -------------------------------------
// 64 WGs x 256 threads. WG = (dir d, slice ns of 16 hidden units).
// ps slice: M=32 batch x N=80 (5 gates x 16) x K=512, K-split over 4 waves.
__global__ __launch_bounds__(256) void k_step(
    const unsigned short* __restrict__ px,    // [2][16384][3072] bf16
    const unsigned short* __restrict__ wp,    // this layer: [2 dir][5][32][16][512]
    const float* __restrict__ bias_f, const float* __restrict__ bias_b,
    const unsigned short* __restrict__ h_in,  // [2][32][512] bf16
    unsigned short* __restrict__ h_out,
    float* __restrict__ cbuf,                 // [2][32][512] f32
    unsigned short* __restrict__ ybf,         // layer0: a1bf, else null
    float* __restrict__ yf,                   // layer1: d_out, else null
    float* __restrict__ finals,               // d_out + 16777216
    int s, int layer) {
  __shared__ float part[4][32][80];           // 40 KiB
  int wg = blockIdx.x;
  int d = wg >> 5, ns = wg & 31, j0 = ns * 16;
  int tid = threadIdx.x;
  int w = tid >> 6, l = tid & 63;
  int t = d ? (511 - s) : s;
  const unsigned short* hb = h_in + d * (32 * 512);
  const unsigned short* wpd = wp + (size_t)d * 1310720;

  f32x4 acc[2][5];
#pragma unroll
  for (int m = 0; m < 2; ++m)
#pragma unroll
    for (int g = 0; g < 5; ++g) acc[m][g] = (f32x4){0.f, 0.f, 0.f, 0.f};

#pragma unroll
  for (int kk = 0; kk < 4; ++kk) {
    int ks = w * 4 + kk;
    int k0 = ks * 32;
    bf16x8 a[2];
#pragma unroll
    for (int m = 0; m < 2; ++m) {
      int row = m * 16 + (l & 15);
      a[m] = __builtin_bit_cast(bf16x8, *(const us8*)&hb[row * 512 + k0 + ((l >> 4) << 3)]);
    }
#pragma unroll
    for (int g = 0; g < 5; ++g) {
      bf16x8 bfr = __builtin_bit_cast(
          bf16x8, *(const us8*)&wpd[(size_t)((g * 32 + ns) * 16 + ks) * 512 + l * 8]);
      acc[0][g] = MFMA(a[0], bfr, acc[0][g]);
      acc[1][g] = MFMA(a[1], bfr, acc[1][g]);
    }
  }
#pragma unroll
  for (int m = 0; m < 2; ++m)
#pragma unroll
    for (int g = 0; g < 5; ++g)
#pragma unroll
      for (int r4 = 0; r4 < 4; ++r4)
        part[w][m * 16 + (l >> 4) * 4 + r4][g * 16 + (l & 15)] = acc[m][g][r4];
  __syncthreads();

  const float* bias = d ? bias_b : bias_f;
  const unsigned short* pxd = px + (size_t)d * 16384 * 3072;
#pragma unroll
  for (int p = 0; p < 2; ++p) {
    int idx = tid + p * 256;                 // 0..511
    int b_ = idx >> 4, j = idx & 15, jg = j0 + j;
    float ps[5];
#pragma unroll
    for (int g = 0; g < 5; ++g) {
      int c = g * 16 + j;
      ps[g] = part[0][b_][c] + part[1][b_][c] + part[2][b_][c] + part[3][b_][c] +
              bias[g * 512 + jg];
    }
    size_t po = ((size_t)(b_ * 512 + t)) * 3072 + jg;
    float x0 = bf2f(pxd[po]);
    float x1 = bf2f(pxd[po + 512]);
    float x2 = bf2f(pxd[po + 1024]);
    float x3 = bf2f(pxd[po + 1536]);
    float x4 = bf2f(pxd[po + 2048]);
    float x5 = bf2f(pxd[po + 2560]);
    float iG = sigf(x0 + ps[0]);
    float fG = sigf(x1 + ps[1]);
    float gG = tanh_(x2 + ps[2]);
    float oG = sigf(x3 + ps[3]);
    int ci = (d * 32 + b_) * 512 + jg;
    float cp = (s == 0) ? 0.f : cbuf[ci];
    float cn = iG * gG + fG * cp;
    float ht = oG * tanh_(cn);
    float rG = sigf(x4 + ps[4]);
    ht = rG * ht + (1.f - rG) * x5;
    cbuf[ci] = cn;
    h_out[ci] = f2bf(ht);
    size_t yo = ((size_t)(b_ * 512 + t)) * 1024 + d * 512 + jg;
    if (ybf) ybf[yo] = f2bf(ht);
    if (yf) yf[yo] = ht;
    if (s == 511) {
      int fo = (layer * 32 + b_) * 1024 + d * 512 + jg;
      finals[fo] = ht;            // final_h
      finals[65536 + fo] = cn;    // final_c
    }
  }
}

// --------------------------- host ------------------------------------------

extern "C" void kernel_launch(void* const* d_in, const int* in_sizes, int n_in,
                              void* d_out, int out_size, void* d_ws, size_t ws_size,
                              hipStream_t stream) {
  (void)in_sizes; (void)n_in; (void)out_size; (void)ws_size;
  const float* x = (const float*)d_in[0];
  const float* Wx[4] = {(const float*)d_in[1], (const float*)d_in[4],
                        (const float*)d_in[7], (const float*)d_in[10]};
  const float* Wh[4] = {(const float*)d_in[2], (const float*)d_in[5],
                        (const float*)d_in[8], (const float*)d_in[11]};
  const float* bs[4] = {(const float*)d_in[3], (const float*)d_in[6],
                        (const float*)d_in[9], (const float*)d_in[12]};

  // ws: only the irreducible live set (~202.3 MiB)
  char* ws = (char*)d_ws;
  unsigned short* px   = (unsigned short*)(ws);
  unsigned short* whp  = (unsigned short*)(ws + 201326592);
  unsigned short* hbf  = (unsigned short*)(ws + 211812352);
  float* cbuf          = (float*)(ws + 211943424);

  // d_out doubles as scratch for transients (all dead before final y writes)
  char* ob = (char*)d_out;
  unsigned short* xbf  = (unsigned short*)(ob);             // 16 MiB, phase A
  unsigned short* wxt0 = (unsigned short*)(ob + 16777216);  // 6 MiB, phase A
  unsigned short* wxt1 = (unsigned short*)(ob + 33554432);  // 12 MiB
  unsigned short* a1bf = (unsigned short*)(ob);             // 32 MiB, phase B
  float* out = (float*)d_out;
  float* finals = out + 16777216;

  k_convert_x<<<8192, 256, 0, stream>>>(x, xbf, 2097152);
  k_pack_wxT<<<dim3(12, 4), 256, 0, stream>>>(Wx[0], Wx[1], Wx[2], Wx[3], wxt0, wxt1);
  k_pack_whp<<<dim3(640, 4), 256, 0, stream>>>(Wh[0], Wh[1], Wh[2], Wh[3], whp);

  for (int layer = 0; layer < 2; ++layer) {
    int K = layer ? 1024 : 512;
    const unsigned short* Ag = layer ? a1bf : xbf;
    const unsigned short* wxt = layer ? wxt1 : wxt0;
    k_gemm<<<dim3(128, 24, 2), 256, 0, stream>>>(Ag, wxt, px, K);
    hipMemsetAsync(hbf, 0, 131072, stream);   // zero both h double-buffers
    for (int s = 0; s < 512; ++s) {
      k_step<<<64, 256, 0, stream>>>(
          px, whp + (size_t)layer * 2621440, bs[layer * 2], bs[layer * 2 + 1],
          hbf + (size_t)(s & 1) * 32768, hbf + (size_t)((s + 1) & 1) * 32768,
          cbuf, layer ? nullptr : a1bf, layer ? out : nullptr, finals, s, layer);
    }
  }
}